// Round 13
// baseline (60.778 us; speedup 1.0000x reference)
//
#include <hip/hip_runtime.h>

#define TT 8192
#define DD 512
#define EE 32
#define HH 128
#define NRB 256  // router blocks (32 tokens each)

typedef float f32x4 __attribute__((ext_vector_type(4)));
typedef __bf16 bf16x8 __attribute__((ext_vector_type(8)));
typedef unsigned short u16x8 __attribute__((ext_vector_type(8)));

__device__ __forceinline__ unsigned short f2bf(float f) {
  unsigned int u = __builtin_bit_cast(unsigned int, f);
  u = (u + 0x7FFFu + ((u >> 16) & 1u)) >> 16;
  return (unsigned short)u;
}
__device__ __forceinline__ float bf2f(unsigned short h) {
  return __builtin_bit_cast(float, (unsigned int)h << 16);
}

#define GLD16(g, l)                                                            \
  __builtin_amdgcn_global_load_lds(                                            \
      (const __attribute__((address_space(1))) unsigned int*)(g),              \
      (__attribute__((address_space(3))) unsigned int*)(l), 16, 0, 0)

// Fused prep (512 threads): blocks 0..255 = MFMA router, 8 waves = 2 M-halves x 4
// K-quarters (exact 3x3 bf16 split in-register, per-(expert,block) cell lists);
// blocks 256..1279 = keys/values LDS-tiled transpose+convert.
__global__ __launch_bounds__(512) void prep_kernel(
    const float* __restrict__ x, const float* __restrict__ esel,
    const float* __restrict__ keys, const float* __restrict__ values,
    unsigned short* __restrict__ keysT, unsigned short* __restrict__ valuesT,
    unsigned short* __restrict__ xb, int* __restrict__ ccnt,
    int* __restrict__ etok, float* __restrict__ ew) {
  const int tid = threadIdx.x;
  int bid = blockIdx.x;
  if (bid < NRB) {
    // ---------------- router ----------------
    __shared__ float ls[4][32][33];
    __shared__ int bcnt[EE], bcur[EE];
    const int tok0 = bid * 32;
    const int wv = tid >> 6, lane = tid & 63;
    const int mh = wv & 1;    // token-row half (16 rows)
    const int kq = wv >> 1;   // K quarter (4 k-steps)
    const int ll = lane & 15, lh = lane >> 4;
    const int row = tok0 + mh * 16 + ll;

    const float* xr = x + (size_t)row * DD + lh * 8;
    unsigned short* xbr = xb + (size_t)row * DD + lh * 8;
    const float* e0 = esel + (size_t)ll * DD + lh * 8;
    const float* e1 = esel + (size_t)(ll + 16) * DD + lh * 8;

    f32x4 acc0, acc1;
    acc0[0] = 0.f; acc0[1] = 0.f; acc0[2] = 0.f; acc0[3] = 0.f;
    acc1 = acc0;

#pragma unroll 2
    for (int kl = 0; kl < 4; kl++) {
      int k = kq * 4 + kl;
      float4 v0 = *(const float4*)(xr + k * 32);
      float4 v1 = *(const float4*)(xr + k * 32 + 4);
      float vv[8] = {v0.x, v0.y, v0.z, v0.w, v1.x, v1.y, v1.z, v1.w};
      bf16x8 ah, al, al2;
      unsigned short hs[8];
#pragma unroll
      for (int j = 0; j < 8; j++) {
        unsigned short hh = f2bf(vv[j]);
        float r1 = vv[j] - bf2f(hh);
        unsigned short lo = f2bf(r1);
        float r2 = r1 - bf2f(lo);
        hs[j] = hh;
        ah[j] = __builtin_bit_cast(__bf16, hh);
        al[j] = __builtin_bit_cast(__bf16, lo);
        al2[j] = __builtin_bit_cast(__bf16, f2bf(r2));
      }
      *(ushort4*)(xbr + k * 32) = *(ushort4*)&hs[0];
      *(ushort4*)(xbr + k * 32 + 4) = *(ushort4*)&hs[4];

      float4 c00 = *(const float4*)(e0 + k * 32);
      float4 c01 = *(const float4*)(e0 + k * 32 + 4);
      float4 c10 = *(const float4*)(e1 + k * 32);
      float4 c11 = *(const float4*)(e1 + k * 32 + 4);
      float ea[8] = {c00.x, c00.y, c00.z, c00.w, c01.x, c01.y, c01.z, c01.w};
      float eb[8] = {c10.x, c10.y, c10.z, c10.w, c11.x, c11.y, c11.z, c11.w};
      bf16x8 bh0, bl0, bm0, bh1, bl1, bm1;
#pragma unroll
      for (int j = 0; j < 8; j++) {
        unsigned short hh = f2bf(ea[j]);
        float r1 = ea[j] - bf2f(hh);
        unsigned short lo = f2bf(r1);
        float r2 = r1 - bf2f(lo);
        bh0[j] = __builtin_bit_cast(__bf16, hh);
        bl0[j] = __builtin_bit_cast(__bf16, lo);
        bm0[j] = __builtin_bit_cast(__bf16, f2bf(r2));
        hh = f2bf(eb[j]);
        r1 = eb[j] - bf2f(hh);
        lo = f2bf(r1);
        r2 = r1 - bf2f(lo);
        bh1[j] = __builtin_bit_cast(__bf16, hh);
        bl1[j] = __builtin_bit_cast(__bf16, lo);
        bm1[j] = __builtin_bit_cast(__bf16, f2bf(r2));
      }

      acc0 = __builtin_amdgcn_mfma_f32_16x16x32_bf16(ah, bh0, acc0, 0, 0, 0);
      acc0 = __builtin_amdgcn_mfma_f32_16x16x32_bf16(ah, bl0, acc0, 0, 0, 0);
      acc0 = __builtin_amdgcn_mfma_f32_16x16x32_bf16(al, bh0, acc0, 0, 0, 0);
      acc0 = __builtin_amdgcn_mfma_f32_16x16x32_bf16(ah, bm0, acc0, 0, 0, 0);
      acc0 = __builtin_amdgcn_mfma_f32_16x16x32_bf16(al, bl0, acc0, 0, 0, 0);
      acc0 = __builtin_amdgcn_mfma_f32_16x16x32_bf16(al2, bh0, acc0, 0, 0, 0);

      acc1 = __builtin_amdgcn_mfma_f32_16x16x32_bf16(ah, bh1, acc1, 0, 0, 0);
      acc1 = __builtin_amdgcn_mfma_f32_16x16x32_bf16(ah, bl1, acc1, 0, 0, 0);
      acc1 = __builtin_amdgcn_mfma_f32_16x16x32_bf16(al, bh1, acc1, 0, 0, 0);
      acc1 = __builtin_amdgcn_mfma_f32_16x16x32_bf16(ah, bm1, acc1, 0, 0, 0);
      acc1 = __builtin_amdgcn_mfma_f32_16x16x32_bf16(al, bl1, acc1, 0, 0, 0);
      acc1 = __builtin_amdgcn_mfma_f32_16x16x32_bf16(al2, bh1, acc1, 0, 0, 0);
    }

#pragma unroll
    for (int r = 0; r < 4; r++) {
      ls[kq][mh * 16 + lh * 4 + r][ll] = acc0[r];
      ls[kq][mh * 16 + lh * 4 + r][16 + ll] = acc1[r];
    }
    if (tid < EE) bcnt[tid] = 0;
    __syncthreads();

    int i0 = 0, i1 = 0;
    float w0 = 0.f, w1 = 0.f;
    if (tid < 32) {
      float m0 = -3.4e38f;
#pragma unroll
      for (int e2 = 0; e2 < EE; e2++) {
        float v = ls[0][tid][e2] + ls[1][tid][e2] + ls[2][tid][e2] + ls[3][tid][e2];
        if (v > m0) { m0 = v; i0 = e2; }
      }
      float m1 = -3.4e38f;
      i1 = (i0 == 0) ? 1 : 0;
#pragma unroll
      for (int e2 = 0; e2 < EE; e2++) {
        float v = ls[0][tid][e2] + ls[1][tid][e2] + ls[2][tid][e2] + ls[3][tid][e2];
        if (e2 != i0 && v > m1) { m1 = v; i1 = e2; }
      }
      w0 = 1.f / (1.f + expf(-m0));
      w1 = 1.f / (1.f + expf(-m1));
      atomicAdd(&bcnt[i0], 1);
      atomicAdd(&bcnt[i1], 1);
    }
    __syncthreads();
    if (tid < EE) { ccnt[tid * NRB + bid] = bcnt[tid]; bcur[tid] = 0; }
    __syncthreads();
    if (tid < 32) {
      int t = tok0 + tid;
      int p0 = atomicAdd(&bcur[i0], 1);
      etok[((size_t)i0 * NRB + bid) * 32 + p0] = t;              // slot 0
      ew[((size_t)i0 * NRB + bid) * 32 + p0] = w0;
      int p1 = atomicAdd(&bcur[i1], 1);
      etok[((size_t)i1 * NRB + bid) * 32 + p1] = t | (1 << 20);  // slot 1
      ew[((size_t)i1 * NRB + bid) * 32 + p1] = w1;
    }
    return;
  }
  // ---------------- keys/values transpose+convert (512 threads) ----------------
  bid -= NRB;  // 0..1023
  __shared__ float tile[64][68];
  const float* src;
  unsigned short* dst;
  int R, C, r0, c0, e;
  if (bid < 512) {
    e = bid >> 4; int sub = bid & 15;
    R = DD; C = HH; r0 = (sub >> 1) * 64; c0 = (sub & 1) * 64;
    src = keys; dst = keysT;
  } else {
    bid -= 512;
    e = bid >> 4; int sub = bid & 15;
    R = HH; C = DD; r0 = (sub & 1) * 64; c0 = (sub >> 1) * 64;
    src = values; dst = valuesT;
  }
  const int rl = tid >> 3, cq = (tid & 7) * 8;
  const float* s0 = src + ((size_t)e * R + r0 + rl) * C + c0 + cq;
  *(float4*)&tile[rl][cq] = *(const float4*)(s0);
  *(float4*)&tile[rl][cq + 4] = *(const float4*)(s0 + 4);
  __syncthreads();
  unsigned short* d0 = dst + ((size_t)e * C + c0 + rl) * R + r0 + cq;
#pragma unroll
  for (int i = 0; i < 2; i++) {
    ushort4 v;
    v.x = f2bf(tile[cq + 4 * i + 0][rl]);
    v.y = f2bf(tile[cq + 4 * i + 1][rl]);
    v.z = f2bf(tile[cq + 4 * i + 2][rl]);
    v.w = f2bf(tile[cq + 4 * i + 3][rl]);
    *(ushort4*)(d0 + 4 * i) = v;
  }
}

// Grouped expert GEMM (R11 core), 8 waves, LDS-staged B (dbuf + XOR swizzle).
// Grid-stride over 64-token tiles (grid 32x32): kills the no-op dispatch tail
// while staying correct for arbitrary routing skew (cnt up to TT).
__global__ __launch_bounds__(512) void moe_gemm_kernel(
    const unsigned short* __restrict__ xb,
    const unsigned short* __restrict__ keysT,
    const unsigned short* __restrict__ valuesT,
    const int* __restrict__ ccnt,
    const int* __restrict__ etok,
    const float* __restrict__ ew,
    unsigned short* __restrict__ yb) {
  const int e = blockIdx.x;

  __shared__ int csc[NRB];
  __shared__ int cnt_s;
  __shared__ unsigned short stage_buf[2][8192];
  __shared__ unsigned short h_swz[8192];  // GEMM1 h tile; reused as y-chunk LDS in GEMM2
  __shared__ int tok_s[64];
  __shared__ int srow_s[64];
  __shared__ float w_s[64];

  const int tid = threadIdx.x;
  const int lane = tid & 63;
  const int wv = tid >> 6;

  // wave-0 inclusive scan of this expert's 256 cell counts (int4/lane + shfl)
  if (wv == 0) {
    int4 c4 = *(const int4*)(ccnt + e * NRB + lane * 4);
    int s0 = c4.x, s1 = s0 + c4.y, s2 = s1 + c4.z, s3 = s2 + c4.w;
    int tot = s3;
    for (int off = 1; off < 64; off <<= 1) {
      int n = __shfl_up(tot, off);
      if (lane >= off) tot += n;
    }
    int b0 = tot - s3;
    csc[lane * 4 + 0] = b0 + s0;
    csc[lane * 4 + 1] = b0 + s1;
    csc[lane * 4 + 2] = b0 + s2;
    csc[lane * 4 + 3] = b0 + s3;
    if (lane == 63) cnt_s = tot;
  }
  __syncthreads();
  const int cnt = cnt_s;

  const int wm = wv & 3;
  const int wn = wv >> 2;
  const int ll = lane & 15, lh = lane >> 4;

  const unsigned short* kT = keysT + (size_t)e * HH * DD;
  const unsigned short* vT = valuesT + (size_t)e * DD * HH;

  auto stage_b1 = [&](int c, int b) {
#pragma unroll
    for (int i = 0; i < 2; i++) {
      int P = (i * 512 + tid) * 16;
      int n = P >> 7;
      int q = P & 127;
      const char* g = (const char*)(kT + (size_t)n * DD + c * 64) + (q ^ ((n & 7) << 4));
      char* l = (char*)stage_buf[b] + (i * 512 + (tid & ~63)) * 16;
      GLD16(g, l);
    }
  };
  auto stage_b2 = [&](int c, int b) {
#pragma unroll
    for (int i = 0; i < 2; i++) {
      int P = (i * 512 + tid) * 16;
      int r = P >> 8;
      int q = P & 255;
      const char* g = (const char*)(vT + (size_t)(c * 64 + r) * HH) + (q ^ ((r & 7) << 4));
      char* l = (char*)stage_buf[b] + (i * 512 + (tid & ~63)) * 16;
      GLD16(g, l);
    }
  };

  for (int tile = blockIdx.y; tile * 64 < cnt; tile += 32) {
    const int base = tile * 64;

    stage_b1(0, 0);
    if (tid < 64) {
      int i = base + tid;
      bool valid = i < cnt;
      int ie = valid ? i : (cnt - 1);
      int lo = 0, hi = NRB - 1;
      while (lo < hi) { int mid = (lo + hi) >> 1; if (csc[mid] > ie) hi = mid; else lo = mid + 1; }
      int prev = lo ? csc[lo - 1] : 0;
      size_t cell = ((size_t)e * NRB + lo) * 32 + (ie - prev);
      int v = etok[cell];
      int t = v & 0xFFFFF;
      tok_s[tid] = t;
      srow_s[tid] = valid ? ((v >> 20) * (TT + 1) + t) : TT;  // dump row when padding
      w_s[tid] = valid ? ew[cell] : 0.f;
    }
    __syncthreads();

    const unsigned short* ap = xb + (size_t)tok_s[wm * 16 + ll] * DD;

    f32x4 acc[4];
#pragma unroll
    for (int n = 0; n < 4; n++) { acc[n][0] = 0.f; acc[n][1] = 0.f; acc[n][2] = 0.f; acc[n][3] = 0.f; }

    for (int c = 0; c < 8; c++) {
      if (c < 7) stage_b1(c + 1, (c + 1) & 1);
      else       stage_b2(0, 0);
      const char* sb = (const char*)stage_buf[c & 1];
#pragma unroll
      for (int kkl = 0; kkl < 2; kkl++) {
        bf16x8 af = *(const bf16x8*)(ap + c * 64 + kkl * 32 + lh * 8);
#pragma unroll
        for (int nt = 0; nt < 4; nt++) {
          int n = wn * 64 + nt * 16 + ll;
          int boff = n * 128 + ((kkl * 64 + lh * 16) ^ ((n & 7) << 4));
          bf16x8 bfr = *(const bf16x8*)(sb + boff);
          acc[nt] = __builtin_amdgcn_mfma_f32_16x16x32_bf16(af, bfr, acc[nt], 0, 0, 0);
        }
      }
      __syncthreads();
    }

#pragma unroll
    for (int nt = 0; nt < 4; nt++) {
#pragma unroll
      for (int r = 0; r < 4; r++) {
        int row = wm * 16 + lh * 4 + r;
        int col = wn * 64 + nt * 16 + ll;
        int off = row * 256 + ((col * 2) ^ ((row & 7) << 4));
        *(unsigned short*)((char*)h_swz + off) = f2bf(fmaxf(acc[nt][r], 0.f));
      }
    }
    __syncthreads();

    bf16x8 a2[4];
#pragma unroll
    for (int kk = 0; kk < 4; kk++) {
      int row = wm * 16 + ll;
      int off = row * 256 + ((kk * 64 + lh * 16) ^ ((row & 7) << 4));
      a2[kk] = *(const bf16x8*)((const char*)h_swz + off);
    }

    float wr[4];
#pragma unroll
    for (int r = 0; r < 4; r++) wr[r] = w_s[wm * 16 + lh * 4 + r];

    __syncthreads();  // all a2 reads done; h_swz reusable as y_lds
    unsigned short* y_lds = h_swz;

    for (int c = 0; c < 8; c++) {
      if (c < 7) stage_b2(c + 1, (c + 1) & 1);
      const char* sb = (const char*)stage_buf[c & 1];
#pragma unroll
      for (int ntl = 0; ntl < 2; ntl++) {
        f32x4 c2;
        c2[0] = 0.f; c2[1] = 0.f; c2[2] = 0.f; c2[3] = 0.f;
#pragma unroll
        for (int kk = 0; kk < 4; kk++) {
          int r = wn * 32 + ntl * 16 + ll;
          int boff = r * 256 + ((kk * 64 + lh * 16) ^ ((r & 7) << 4));
          bf16x8 bfr = *(const bf16x8*)(sb + boff);
          c2 = __builtin_amdgcn_mfma_f32_16x16x32_bf16(a2[kk], bfr, c2, 0, 0, 0);
        }
        int colb = wn * 32 + ntl * 16 + ll;  // 0..63 within this c-chunk
#pragma unroll
        for (int r = 0; r < 4; r++) {
          int row = wm * 16 + lh * 4 + r;
          int off = row * 128 + ((colb * 2) ^ ((row & 7) << 4));
          *(unsigned short*)((char*)y_lds + off) = f2bf(c2[r] * wr[r]);
        }
      }
      __syncthreads();
      {
        int rr = tid >> 3, g = tid & 7;
        int off = rr * 128 + ((g * 16) ^ ((rr & 7) << 4));
        u16x8 v = *(const u16x8*)((const char*)y_lds + off);
        *(u16x8*)(yb + (size_t)srow_s[rr] * DD + c * 64 + g * 8) = v;
      }
      __syncthreads();
    }
  }
}

// out[t][d] = ybuf[0][t][d] + ybuf[1][t][d]  (bf16 in, f32 out)
__global__ __launch_bounds__(256) void combine_kernel(const unsigned short* __restrict__ yb,
                                                      float* __restrict__ out) {
  size_t i = ((size_t)blockIdx.x * 256 + threadIdx.x) * 8;
  u16x8 a = *(const u16x8*)(yb + i);
  u16x8 b = *(const u16x8*)(yb + (size_t)(TT + 1) * DD + i);
  float4 o0, o1;
  o0.x = bf2f(a[0]) + bf2f(b[0]);
  o0.y = bf2f(a[1]) + bf2f(b[1]);
  o0.z = bf2f(a[2]) + bf2f(b[2]);
  o0.w = bf2f(a[3]) + bf2f(b[3]);
  o1.x = bf2f(a[4]) + bf2f(b[4]);
  o1.y = bf2f(a[5]) + bf2f(b[5]);
  o1.z = bf2f(a[6]) + bf2f(b[6]);
  o1.w = bf2f(a[7]) + bf2f(b[7]);
  *(float4*)(out + i) = o0;
  *(float4*)(out + i + 4) = o1;
}

extern "C" void kernel_launch(void* const* d_in, const int* in_sizes, int n_in,
                              void* d_out, int out_size, void* d_ws, size_t ws_size,
                              hipStream_t stream) {
  const float* x = (const float*)d_in[0];
  const float* esel = (const float*)d_in[1];
  const float* keys = (const float*)d_in[2];
  const float* values = (const float*)d_in[3];
  float* out = (float*)d_out;

  char* p = (char*)d_ws;
  unsigned short* xb = (unsigned short*)p;      p += (size_t)TT * DD * 2;
  unsigned short* keysT = (unsigned short*)p;   p += (size_t)EE * DD * HH * 2;
  unsigned short* valuesT = (unsigned short*)p; p += (size_t)EE * DD * HH * 2;
  int* ccnt = (int*)p;                          p += (size_t)EE * NRB * 4;
  int* etok = (int*)p;                          p += (size_t)EE * NRB * 32 * 4;
  float* ew = (float*)p;                        p += (size_t)EE * NRB * 32 * 4;
  unsigned short* yb = (unsigned short*)p;      p += (size_t)2 * (TT + 1) * DD * 2;

  prep_kernel<<<NRB + 1024, 512, 0, stream>>>(x, esel, keys, values, keysT, valuesT,
                                              xb, ccnt, etok, ew);
  moe_gemm_kernel<<<dim3(EE, 32), 512, 0, stream>>>(xb, keysT, valuesT, ccnt, etok, ew, yb);
  combine_kernel<<<(TT * DD / 8) / 256, 256, 0, stream>>>(yb, out);
}

// Round 14
// 55.222 us; speedup vs baseline: 1.1006x; 1.1006x over previous
//
#include <hip/hip_runtime.h>

#define TT 8192
#define DD 512
#define EE 32
#define HH 128
#define NRB 256  // router blocks (32 tokens each)

typedef float f32x4 __attribute__((ext_vector_type(4)));
typedef __bf16 bf16x8 __attribute__((ext_vector_type(8)));
typedef unsigned short u16x8 __attribute__((ext_vector_type(8)));

__device__ __forceinline__ unsigned short f2bf(float f) {
  unsigned int u = __builtin_bit_cast(unsigned int, f);
  u = (u + 0x7FFFu + ((u >> 16) & 1u)) >> 16;
  return (unsigned short)u;
}
__device__ __forceinline__ float bf2f(unsigned short h) {
  return __builtin_bit_cast(float, (unsigned int)h << 16);
}

#define GLD16(g, l)                                                            \
  __builtin_amdgcn_global_load_lds(                                            \
      (const __attribute__((address_space(1))) unsigned int*)(g),              \
      (__attribute__((address_space(3))) unsigned int*)(l), 16, 0, 0)

// Fused prep (512 threads): blocks 0..255 = MFMA router, 8 waves = 2 M-halves x 4
// K-quarters (exact 3x3 bf16 split in-register, per-(expert,block) cell lists);
// blocks 256..1279 = keys/values LDS-tiled transpose+convert.
// Also accumulates per-expert totals into cntg (device atomics, order-independent).
__global__ __launch_bounds__(512) void prep_kernel(
    const float* __restrict__ x, const float* __restrict__ esel,
    const float* __restrict__ keys, const float* __restrict__ values,
    unsigned short* __restrict__ keysT, unsigned short* __restrict__ valuesT,
    unsigned short* __restrict__ xb, int* __restrict__ ccnt,
    int* __restrict__ etok, float* __restrict__ ew, int* __restrict__ cntg) {
  const int tid = threadIdx.x;
  int bid = blockIdx.x;
  if (bid < NRB) {
    // ---------------- router ----------------
    __shared__ float ls[4][32][33];
    __shared__ int bcnt[EE], bcur[EE];
    const int tok0 = bid * 32;
    const int wv = tid >> 6, lane = tid & 63;
    const int mh = wv & 1;    // token-row half (16 rows)
    const int kq = wv >> 1;   // K quarter (4 k-steps)
    const int ll = lane & 15, lh = lane >> 4;
    const int row = tok0 + mh * 16 + ll;

    const float* xr = x + (size_t)row * DD + lh * 8;
    unsigned short* xbr = xb + (size_t)row * DD + lh * 8;
    const float* e0 = esel + (size_t)ll * DD + lh * 8;
    const float* e1 = esel + (size_t)(ll + 16) * DD + lh * 8;

    f32x4 acc0, acc1;
    acc0[0] = 0.f; acc0[1] = 0.f; acc0[2] = 0.f; acc0[3] = 0.f;
    acc1 = acc0;

#pragma unroll 2
    for (int kl = 0; kl < 4; kl++) {
      int k = kq * 4 + kl;
      float4 v0 = *(const float4*)(xr + k * 32);
      float4 v1 = *(const float4*)(xr + k * 32 + 4);
      float vv[8] = {v0.x, v0.y, v0.z, v0.w, v1.x, v1.y, v1.z, v1.w};
      bf16x8 ah, al, al2;
      unsigned short hs[8];
#pragma unroll
      for (int j = 0; j < 8; j++) {
        unsigned short hh = f2bf(vv[j]);
        float r1 = vv[j] - bf2f(hh);
        unsigned short lo = f2bf(r1);
        float r2 = r1 - bf2f(lo);
        hs[j] = hh;
        ah[j] = __builtin_bit_cast(__bf16, hh);
        al[j] = __builtin_bit_cast(__bf16, lo);
        al2[j] = __builtin_bit_cast(__bf16, f2bf(r2));
      }
      *(ushort4*)(xbr + k * 32) = *(ushort4*)&hs[0];
      *(ushort4*)(xbr + k * 32 + 4) = *(ushort4*)&hs[4];

      float4 c00 = *(const float4*)(e0 + k * 32);
      float4 c01 = *(const float4*)(e0 + k * 32 + 4);
      float4 c10 = *(const float4*)(e1 + k * 32);
      float4 c11 = *(const float4*)(e1 + k * 32 + 4);
      float ea[8] = {c00.x, c00.y, c00.z, c00.w, c01.x, c01.y, c01.z, c01.w};
      float eb[8] = {c10.x, c10.y, c10.z, c10.w, c11.x, c11.y, c11.z, c11.w};
      bf16x8 bh0, bl0, bm0, bh1, bl1, bm1;
#pragma unroll
      for (int j = 0; j < 8; j++) {
        unsigned short hh = f2bf(ea[j]);
        float r1 = ea[j] - bf2f(hh);
        unsigned short lo = f2bf(r1);
        float r2 = r1 - bf2f(lo);
        bh0[j] = __builtin_bit_cast(__bf16, hh);
        bl0[j] = __builtin_bit_cast(__bf16, lo);
        bm0[j] = __builtin_bit_cast(__bf16, f2bf(r2));
        hh = f2bf(eb[j]);
        r1 = eb[j] - bf2f(hh);
        lo = f2bf(r1);
        r2 = r1 - bf2f(lo);
        bh1[j] = __builtin_bit_cast(__bf16, hh);
        bl1[j] = __builtin_bit_cast(__bf16, lo);
        bm1[j] = __builtin_bit_cast(__bf16, f2bf(r2));
      }

      acc0 = __builtin_amdgcn_mfma_f32_16x16x32_bf16(ah, bh0, acc0, 0, 0, 0);
      acc0 = __builtin_amdgcn_mfma_f32_16x16x32_bf16(ah, bl0, acc0, 0, 0, 0);
      acc0 = __builtin_amdgcn_mfma_f32_16x16x32_bf16(al, bh0, acc0, 0, 0, 0);
      acc0 = __builtin_amdgcn_mfma_f32_16x16x32_bf16(ah, bm0, acc0, 0, 0, 0);
      acc0 = __builtin_amdgcn_mfma_f32_16x16x32_bf16(al, bl0, acc0, 0, 0, 0);
      acc0 = __builtin_amdgcn_mfma_f32_16x16x32_bf16(al2, bh0, acc0, 0, 0, 0);

      acc1 = __builtin_amdgcn_mfma_f32_16x16x32_bf16(ah, bh1, acc1, 0, 0, 0);
      acc1 = __builtin_amdgcn_mfma_f32_16x16x32_bf16(ah, bl1, acc1, 0, 0, 0);
      acc1 = __builtin_amdgcn_mfma_f32_16x16x32_bf16(al, bh1, acc1, 0, 0, 0);
      acc1 = __builtin_amdgcn_mfma_f32_16x16x32_bf16(ah, bm1, acc1, 0, 0, 0);
      acc1 = __builtin_amdgcn_mfma_f32_16x16x32_bf16(al, bl1, acc1, 0, 0, 0);
      acc1 = __builtin_amdgcn_mfma_f32_16x16x32_bf16(al2, bh1, acc1, 0, 0, 0);
    }

#pragma unroll
    for (int r = 0; r < 4; r++) {
      ls[kq][mh * 16 + lh * 4 + r][ll] = acc0[r];
      ls[kq][mh * 16 + lh * 4 + r][16 + ll] = acc1[r];
    }
    if (tid < EE) bcnt[tid] = 0;
    __syncthreads();

    int i0 = 0, i1 = 0;
    float w0 = 0.f, w1 = 0.f;
    if (tid < 32) {
      float m0 = -3.4e38f;
#pragma unroll
      for (int e2 = 0; e2 < EE; e2++) {
        float v = ls[0][tid][e2] + ls[1][tid][e2] + ls[2][tid][e2] + ls[3][tid][e2];
        if (v > m0) { m0 = v; i0 = e2; }
      }
      float m1 = -3.4e38f;
      i1 = (i0 == 0) ? 1 : 0;
#pragma unroll
      for (int e2 = 0; e2 < EE; e2++) {
        float v = ls[0][tid][e2] + ls[1][tid][e2] + ls[2][tid][e2] + ls[3][tid][e2];
        if (e2 != i0 && v > m1) { m1 = v; i1 = e2; }
      }
      w0 = 1.f / (1.f + expf(-m0));
      w1 = 1.f / (1.f + expf(-m1));
      atomicAdd(&bcnt[i0], 1);
      atomicAdd(&bcnt[i1], 1);
    }
    __syncthreads();
    if (tid < EE) {
      ccnt[tid * NRB + bid] = bcnt[tid];
      bcur[tid] = 0;
      atomicAdd(&cntg[tid], bcnt[tid]);  // per-expert total (order-independent sum)
    }
    __syncthreads();
    if (tid < 32) {
      int t = tok0 + tid;
      int p0 = atomicAdd(&bcur[i0], 1);
      etok[((size_t)i0 * NRB + bid) * 32 + p0] = t;              // slot 0
      ew[((size_t)i0 * NRB + bid) * 32 + p0] = w0;
      int p1 = atomicAdd(&bcur[i1], 1);
      etok[((size_t)i1 * NRB + bid) * 32 + p1] = t | (1 << 20);  // slot 1
      ew[((size_t)i1 * NRB + bid) * 32 + p1] = w1;
    }
    return;
  }
  // ---------------- keys/values transpose+convert (512 threads) ----------------
  bid -= NRB;  // 0..1023
  __shared__ float tile[64][68];
  const float* src;
  unsigned short* dst;
  int R, C, r0, c0, e;
  if (bid < 512) {
    e = bid >> 4; int sub = bid & 15;
    R = DD; C = HH; r0 = (sub >> 1) * 64; c0 = (sub & 1) * 64;
    src = keys; dst = keysT;
  } else {
    bid -= 512;
    e = bid >> 4; int sub = bid & 15;
    R = HH; C = DD; r0 = (sub & 1) * 64; c0 = (sub >> 1) * 64;
    src = values; dst = valuesT;
  }
  const int rl = tid >> 3, cq = (tid & 7) * 8;
  const float* s0 = src + ((size_t)e * R + r0 + rl) * C + c0 + cq;
  *(float4*)&tile[rl][cq] = *(const float4*)(s0);
  *(float4*)&tile[rl][cq + 4] = *(const float4*)(s0 + 4);
  __syncthreads();
  unsigned short* d0 = dst + ((size_t)e * C + c0 + rl) * R + r0 + cq;
#pragma unroll
  for (int i = 0; i < 2; i++) {
    ushort4 v;
    v.x = f2bf(tile[cq + 4 * i + 0][rl]);
    v.y = f2bf(tile[cq + 4 * i + 1][rl]);
    v.z = f2bf(tile[cq + 4 * i + 2][rl]);
    v.w = f2bf(tile[cq + 4 * i + 3][rl]);
    *(ushort4*)(d0 + 4 * i) = v;
  }
}

// Grouped expert GEMM (R11 core), 8 waves, LDS-staged B (dbuf + XOR swizzle).
// Pre-scan scalar early exit via cntg; wave-0 shfl-scan only in working blocks.
__global__ __launch_bounds__(512) void moe_gemm_kernel(
    const unsigned short* __restrict__ xb,
    const unsigned short* __restrict__ keysT,
    const unsigned short* __restrict__ valuesT,
    const int* __restrict__ ccnt,
    const int* __restrict__ etok,
    const float* __restrict__ ew,
    const int* __restrict__ cntg,
    unsigned short* __restrict__ yb) {
  const int e = blockIdx.x;
  const int base = blockIdx.y * 64;
  const int cnt = cntg[e];
  if (base >= cnt) return;

  __shared__ int csc[NRB];
  __shared__ unsigned short stage_buf[2][8192];
  __shared__ unsigned short h_swz[8192];  // GEMM1 h tile; reused as y-chunk LDS in GEMM2
  __shared__ int tok_s[64];
  __shared__ int srow_s[64];
  __shared__ float w_s[64];

  const int tid = threadIdx.x;
  const int lane = tid & 63;
  const int wv = tid >> 6;

  // wave-0 inclusive scan of this expert's 256 cell counts (int4/lane + shfl)
  if (wv == 0) {
    int4 c4 = *(const int4*)(ccnt + e * NRB + lane * 4);
    int s0 = c4.x, s1 = s0 + c4.y, s2 = s1 + c4.z, s3 = s2 + c4.w;
    int tot = s3;
    for (int off = 1; off < 64; off <<= 1) {
      int n = __shfl_up(tot, off);
      if (lane >= off) tot += n;
    }
    int b0 = tot - s3;
    csc[lane * 4 + 0] = b0 + s0;
    csc[lane * 4 + 1] = b0 + s1;
    csc[lane * 4 + 2] = b0 + s2;
    csc[lane * 4 + 3] = b0 + s3;
  }

  const int wm = wv & 3;
  const int wn = wv >> 2;
  const int ll = lane & 15, lh = lane >> 4;

  const unsigned short* kT = keysT + (size_t)e * HH * DD;
  const unsigned short* vT = valuesT + (size_t)e * DD * HH;

  auto stage_b1 = [&](int c, int b) {
#pragma unroll
    for (int i = 0; i < 2; i++) {
      int P = (i * 512 + tid) * 16;
      int n = P >> 7;
      int q = P & 127;
      const char* g = (const char*)(kT + (size_t)n * DD + c * 64) + (q ^ ((n & 7) << 4));
      char* l = (char*)stage_buf[b] + (i * 512 + (tid & ~63)) * 16;
      GLD16(g, l);
    }
  };
  auto stage_b2 = [&](int c, int b) {
#pragma unroll
    for (int i = 0; i < 2; i++) {
      int P = (i * 512 + tid) * 16;
      int r = P >> 8;
      int q = P & 255;
      const char* g = (const char*)(vT + (size_t)(c * 64 + r) * HH) + (q ^ ((r & 7) << 4));
      char* l = (char*)stage_buf[b] + (i * 512 + (tid & ~63)) * 16;
      GLD16(g, l);
    }
  };

  stage_b1(0, 0);
  __syncthreads();  // csc visible
  if (tid < 64) {
    int i = base + tid;
    bool valid = i < cnt;
    int ie = valid ? i : (cnt - 1);
    int lo = 0, hi = NRB - 1;
    while (lo < hi) { int mid = (lo + hi) >> 1; if (csc[mid] > ie) hi = mid; else lo = mid + 1; }
    int prev = lo ? csc[lo - 1] : 0;
    size_t cell = ((size_t)e * NRB + lo) * 32 + (ie - prev);
    int v = etok[cell];
    int t = v & 0xFFFFF;
    tok_s[tid] = t;
    srow_s[tid] = valid ? ((v >> 20) * (TT + 1) + t) : TT;  // dump row when padding
    w_s[tid] = valid ? ew[cell] : 0.f;
  }
  __syncthreads();

  const unsigned short* ap = xb + (size_t)tok_s[wm * 16 + ll] * DD;

  f32x4 acc[4];
#pragma unroll
  for (int n = 0; n < 4; n++) { acc[n][0] = 0.f; acc[n][1] = 0.f; acc[n][2] = 0.f; acc[n][3] = 0.f; }

  for (int c = 0; c < 8; c++) {
    if (c < 7) stage_b1(c + 1, (c + 1) & 1);
    else       stage_b2(0, 0);
    const char* sb = (const char*)stage_buf[c & 1];
#pragma unroll
    for (int kkl = 0; kkl < 2; kkl++) {
      bf16x8 af = *(const bf16x8*)(ap + c * 64 + kkl * 32 + lh * 8);
#pragma unroll
      for (int nt = 0; nt < 4; nt++) {
        int n = wn * 64 + nt * 16 + ll;
        int boff = n * 128 + ((kkl * 64 + lh * 16) ^ ((n & 7) << 4));
        bf16x8 bfr = *(const bf16x8*)(sb + boff);
        acc[nt] = __builtin_amdgcn_mfma_f32_16x16x32_bf16(af, bfr, acc[nt], 0, 0, 0);
      }
    }
    __syncthreads();
  }

#pragma unroll
  for (int nt = 0; nt < 4; nt++) {
#pragma unroll
    for (int r = 0; r < 4; r++) {
      int row = wm * 16 + lh * 4 + r;
      int col = wn * 64 + nt * 16 + ll;
      int off = row * 256 + ((col * 2) ^ ((row & 7) << 4));
      *(unsigned short*)((char*)h_swz + off) = f2bf(fmaxf(acc[nt][r], 0.f));
    }
  }
  __syncthreads();

  bf16x8 a2[4];
#pragma unroll
  for (int kk = 0; kk < 4; kk++) {
    int row = wm * 16 + ll;
    int off = row * 256 + ((kk * 64 + lh * 16) ^ ((row & 7) << 4));
    a2[kk] = *(const bf16x8*)((const char*)h_swz + off);
  }

  float wr[4];
#pragma unroll
  for (int r = 0; r < 4; r++) wr[r] = w_s[wm * 16 + lh * 4 + r];

  __syncthreads();  // all a2 reads done; h_swz reusable as y_lds
  unsigned short* y_lds = h_swz;

  for (int c = 0; c < 8; c++) {
    if (c < 7) stage_b2(c + 1, (c + 1) & 1);
    const char* sb = (const char*)stage_buf[c & 1];
#pragma unroll
    for (int ntl = 0; ntl < 2; ntl++) {
      f32x4 c2;
      c2[0] = 0.f; c2[1] = 0.f; c2[2] = 0.f; c2[3] = 0.f;
#pragma unroll
      for (int kk = 0; kk < 4; kk++) {
        int r = wn * 32 + ntl * 16 + ll;
        int boff = r * 256 + ((kk * 64 + lh * 16) ^ ((r & 7) << 4));
        bf16x8 bfr = *(const bf16x8*)(sb + boff);
        c2 = __builtin_amdgcn_mfma_f32_16x16x32_bf16(a2[kk], bfr, c2, 0, 0, 0);
      }
      int colb = wn * 32 + ntl * 16 + ll;  // 0..63 within this c-chunk
#pragma unroll
      for (int r = 0; r < 4; r++) {
        int row = wm * 16 + lh * 4 + r;
        int off = row * 128 + ((colb * 2) ^ ((row & 7) << 4));
        *(unsigned short*)((char*)y_lds + off) = f2bf(c2[r] * wr[r]);
      }
    }
    __syncthreads();
    {
      int rr = tid >> 3, g = tid & 7;
      int off = rr * 128 + ((g * 16) ^ ((rr & 7) << 4));
      u16x8 v = *(const u16x8*)((const char*)y_lds + off);
      *(u16x8*)(yb + (size_t)srow_s[rr] * DD + c * 64 + g * 8) = v;
    }
    __syncthreads();
  }
}

// out[t][d] = ybuf[0][t][d] + ybuf[1][t][d]  (bf16 in, f32 out)
__global__ __launch_bounds__(256) void combine_kernel(const unsigned short* __restrict__ yb,
                                                      float* __restrict__ out) {
  size_t i = ((size_t)blockIdx.x * 256 + threadIdx.x) * 8;
  u16x8 a = *(const u16x8*)(yb + i);
  u16x8 b = *(const u16x8*)(yb + (size_t)(TT + 1) * DD + i);
  float4 o0, o1;
  o0.x = bf2f(a[0]) + bf2f(b[0]);
  o0.y = bf2f(a[1]) + bf2f(b[1]);
  o0.z = bf2f(a[2]) + bf2f(b[2]);
  o0.w = bf2f(a[3]) + bf2f(b[3]);
  o1.x = bf2f(a[4]) + bf2f(b[4]);
  o1.y = bf2f(a[5]) + bf2f(b[5]);
  o1.z = bf2f(a[6]) + bf2f(b[6]);
  o1.w = bf2f(a[7]) + bf2f(b[7]);
  *(float4*)(out + i) = o0;
  *(float4*)(out + i + 4) = o1;
}

// tiny helper: zero the 32 per-expert counters (avoids an extra memset dispatch cost
// being attributed to fill; still one launch, 1 block)
__global__ void zero_cntg(int* __restrict__ cntg) {
  if (threadIdx.x < EE) cntg[threadIdx.x] = 0;
}

extern "C" void kernel_launch(void* const* d_in, const int* in_sizes, int n_in,
                              void* d_out, int out_size, void* d_ws, size_t ws_size,
                              hipStream_t stream) {
  const float* x = (const float*)d_in[0];
  const float* esel = (const float*)d_in[1];
  const float* keys = (const float*)d_in[2];
  const float* values = (const float*)d_in[3];
  float* out = (float*)d_out;

  char* p = (char*)d_ws;
  unsigned short* xb = (unsigned short*)p;      p += (size_t)TT * DD * 2;
  unsigned short* keysT = (unsigned short*)p;   p += (size_t)EE * DD * HH * 2;
  unsigned short* valuesT = (unsigned short*)p; p += (size_t)EE * DD * HH * 2;
  int* ccnt = (int*)p;                          p += (size_t)EE * NRB * 4;
  int* etok = (int*)p;                          p += (size_t)EE * NRB * 32 * 4;
  float* ew = (float*)p;                        p += (size_t)EE * NRB * 32 * 4;
  int* cntg = (int*)p;                          p += 256;
  unsigned short* yb = (unsigned short*)p;      p += (size_t)2 * (TT + 1) * DD * 2;

  zero_cntg<<<1, 64, 0, stream>>>(cntg);
  prep_kernel<<<NRB + 1024, 512, 0, stream>>>(x, esel, keys, values, keysT, valuesT,
                                              xb, ccnt, etok, ew, cntg);
  moe_gemm_kernel<<<dim3(EE, TT / 64), 512, 0, stream>>>(xb, keysT, valuesT, ccnt, etok, ew,
                                                         cntg, yb);
  combine_kernel<<<(TT * DD / 8) / 256, 256, 0, stream>>>(yb, out);
}

// Round 15
// 48.133 us; speedup vs baseline: 1.2627x; 1.1473x over previous
//
#include <hip/hip_runtime.h>

#define TT 8192
#define DD 512
#define EE 32
#define HH 128
#define NRB 256  // router blocks (32 tokens each)

typedef float f32x4 __attribute__((ext_vector_type(4)));
typedef __bf16 bf16x8 __attribute__((ext_vector_type(8)));
typedef unsigned short u16x8 __attribute__((ext_vector_type(8)));

__device__ __forceinline__ unsigned short f2bf(float f) {
  unsigned int u = __builtin_bit_cast(unsigned int, f);
  u = (u + 0x7FFFu + ((u >> 16) & 1u)) >> 16;
  return (unsigned short)u;
}
__device__ __forceinline__ float bf2f(unsigned short h) {
  return __builtin_bit_cast(float, (unsigned int)h << 16);
}

#define GLD16(g, l)                                                            \
  __builtin_amdgcn_global_load_lds(                                            \
      (const __attribute__((address_space(1))) unsigned int*)(g),              \
      (__attribute__((address_space(3))) unsigned int*)(l), 16, 0, 0)

// Fused prep (512 threads): blocks 0..255 = MFMA router, 8 waves = 2 M-halves x 4
// K-quarters (exact 3x3 bf16 split in-register, per-(expert,block) cell lists);
// blocks 256..1279 = keys/values LDS-tiled transpose+convert.
__global__ __launch_bounds__(512) void prep_kernel(
    const float* __restrict__ x, const float* __restrict__ esel,
    const float* __restrict__ keys, const float* __restrict__ values,
    unsigned short* __restrict__ keysT, unsigned short* __restrict__ valuesT,
    unsigned short* __restrict__ xb, int* __restrict__ ccnt,
    int* __restrict__ etok, float* __restrict__ ew) {
  const int tid = threadIdx.x;
  int bid = blockIdx.x;
  if (bid < NRB) {
    // ---------------- router ----------------
    __shared__ float ls[4][32][33];
    __shared__ int bcnt[EE], bcur[EE];
    const int tok0 = bid * 32;
    const int wv = tid >> 6, lane = tid & 63;
    const int mh = wv & 1;    // token-row half (16 rows)
    const int kq = wv >> 1;   // K quarter (4 k-steps)
    const int ll = lane & 15, lh = lane >> 4;
    const int row = tok0 + mh * 16 + ll;

    const float* xr = x + (size_t)row * DD + lh * 8;
    unsigned short* xbr = xb + (size_t)row * DD + lh * 8;
    const float* e0 = esel + (size_t)ll * DD + lh * 8;
    const float* e1 = esel + (size_t)(ll + 16) * DD + lh * 8;

    f32x4 acc0, acc1;
    acc0[0] = 0.f; acc0[1] = 0.f; acc0[2] = 0.f; acc0[3] = 0.f;
    acc1 = acc0;

#pragma unroll 2
    for (int kl = 0; kl < 4; kl++) {
      int k = kq * 4 + kl;
      float4 v0 = *(const float4*)(xr + k * 32);
      float4 v1 = *(const float4*)(xr + k * 32 + 4);
      float vv[8] = {v0.x, v0.y, v0.z, v0.w, v1.x, v1.y, v1.z, v1.w};
      bf16x8 ah, al, al2;
      unsigned short hs[8];
#pragma unroll
      for (int j = 0; j < 8; j++) {
        unsigned short hh = f2bf(vv[j]);
        float r1 = vv[j] - bf2f(hh);
        unsigned short lo = f2bf(r1);
        float r2 = r1 - bf2f(lo);
        hs[j] = hh;
        ah[j] = __builtin_bit_cast(__bf16, hh);
        al[j] = __builtin_bit_cast(__bf16, lo);
        al2[j] = __builtin_bit_cast(__bf16, f2bf(r2));
      }
      *(ushort4*)(xbr + k * 32) = *(ushort4*)&hs[0];
      *(ushort4*)(xbr + k * 32 + 4) = *(ushort4*)&hs[4];

      float4 c00 = *(const float4*)(e0 + k * 32);
      float4 c01 = *(const float4*)(e0 + k * 32 + 4);
      float4 c10 = *(const float4*)(e1 + k * 32);
      float4 c11 = *(const float4*)(e1 + k * 32 + 4);
      float ea[8] = {c00.x, c00.y, c00.z, c00.w, c01.x, c01.y, c01.z, c01.w};
      float eb[8] = {c10.x, c10.y, c10.z, c10.w, c11.x, c11.y, c11.z, c11.w};
      bf16x8 bh0, bl0, bm0, bh1, bl1, bm1;
#pragma unroll
      for (int j = 0; j < 8; j++) {
        unsigned short hh = f2bf(ea[j]);
        float r1 = ea[j] - bf2f(hh);
        unsigned short lo = f2bf(r1);
        float r2 = r1 - bf2f(lo);
        bh0[j] = __builtin_bit_cast(__bf16, hh);
        bl0[j] = __builtin_bit_cast(__bf16, lo);
        bm0[j] = __builtin_bit_cast(__bf16, f2bf(r2));
        hh = f2bf(eb[j]);
        r1 = eb[j] - bf2f(hh);
        lo = f2bf(r1);
        r2 = r1 - bf2f(lo);
        bh1[j] = __builtin_bit_cast(__bf16, hh);
        bl1[j] = __builtin_bit_cast(__bf16, lo);
        bm1[j] = __builtin_bit_cast(__bf16, f2bf(r2));
      }

      acc0 = __builtin_amdgcn_mfma_f32_16x16x32_bf16(ah, bh0, acc0, 0, 0, 0);
      acc0 = __builtin_amdgcn_mfma_f32_16x16x32_bf16(ah, bl0, acc0, 0, 0, 0);
      acc0 = __builtin_amdgcn_mfma_f32_16x16x32_bf16(al, bh0, acc0, 0, 0, 0);
      acc0 = __builtin_amdgcn_mfma_f32_16x16x32_bf16(ah, bm0, acc0, 0, 0, 0);
      acc0 = __builtin_amdgcn_mfma_f32_16x16x32_bf16(al, bl0, acc0, 0, 0, 0);
      acc0 = __builtin_amdgcn_mfma_f32_16x16x32_bf16(al2, bh0, acc0, 0, 0, 0);

      acc1 = __builtin_amdgcn_mfma_f32_16x16x32_bf16(ah, bh1, acc1, 0, 0, 0);
      acc1 = __builtin_amdgcn_mfma_f32_16x16x32_bf16(ah, bl1, acc1, 0, 0, 0);
      acc1 = __builtin_amdgcn_mfma_f32_16x16x32_bf16(al, bh1, acc1, 0, 0, 0);
      acc1 = __builtin_amdgcn_mfma_f32_16x16x32_bf16(ah, bm1, acc1, 0, 0, 0);
      acc1 = __builtin_amdgcn_mfma_f32_16x16x32_bf16(al, bl1, acc1, 0, 0, 0);
      acc1 = __builtin_amdgcn_mfma_f32_16x16x32_bf16(al2, bh1, acc1, 0, 0, 0);
    }

#pragma unroll
    for (int r = 0; r < 4; r++) {
      ls[kq][mh * 16 + lh * 4 + r][ll] = acc0[r];
      ls[kq][mh * 16 + lh * 4 + r][16 + ll] = acc1[r];
    }
    if (tid < EE) bcnt[tid] = 0;
    __syncthreads();

    int i0 = 0, i1 = 0;
    float w0 = 0.f, w1 = 0.f;
    if (tid < 32) {
      float m0 = -3.4e38f;
#pragma unroll
      for (int e2 = 0; e2 < EE; e2++) {
        float v = ls[0][tid][e2] + ls[1][tid][e2] + ls[2][tid][e2] + ls[3][tid][e2];
        if (v > m0) { m0 = v; i0 = e2; }
      }
      float m1 = -3.4e38f;
      i1 = (i0 == 0) ? 1 : 0;
#pragma unroll
      for (int e2 = 0; e2 < EE; e2++) {
        float v = ls[0][tid][e2] + ls[1][tid][e2] + ls[2][tid][e2] + ls[3][tid][e2];
        if (e2 != i0 && v > m1) { m1 = v; i1 = e2; }
      }
      w0 = 1.f / (1.f + expf(-m0));
      w1 = 1.f / (1.f + expf(-m1));
      atomicAdd(&bcnt[i0], 1);
      atomicAdd(&bcnt[i1], 1);
    }
    __syncthreads();
    if (tid < EE) { ccnt[tid * NRB + bid] = bcnt[tid]; bcur[tid] = 0; }
    __syncthreads();
    if (tid < 32) {
      int t = tok0 + tid;
      int p0 = atomicAdd(&bcur[i0], 1);
      etok[((size_t)i0 * NRB + bid) * 32 + p0] = t;              // slot 0
      ew[((size_t)i0 * NRB + bid) * 32 + p0] = w0;
      int p1 = atomicAdd(&bcur[i1], 1);
      etok[((size_t)i1 * NRB + bid) * 32 + p1] = t | (1 << 20);  // slot 1
      ew[((size_t)i1 * NRB + bid) * 32 + p1] = w1;
    }
    return;
  }
  // ---------------- keys/values transpose+convert (512 threads) ----------------
  bid -= NRB;  // 0..1023
  __shared__ float tile[64][68];
  const float* src;
  unsigned short* dst;
  int R, C, r0, c0, e;
  if (bid < 512) {
    e = bid >> 4; int sub = bid & 15;
    R = DD; C = HH; r0 = (sub >> 1) * 64; c0 = (sub & 1) * 64;
    src = keys; dst = keysT;
  } else {
    bid -= 512;
    e = bid >> 4; int sub = bid & 15;
    R = HH; C = DD; r0 = (sub & 1) * 64; c0 = (sub >> 1) * 64;
    src = values; dst = valuesT;
  }
  const int rl = tid >> 3, cq = (tid & 7) * 8;
  const float* s0 = src + ((size_t)e * R + r0 + rl) * C + c0 + cq;
  *(float4*)&tile[rl][cq] = *(const float4*)(s0);
  *(float4*)&tile[rl][cq + 4] = *(const float4*)(s0 + 4);
  __syncthreads();
  unsigned short* d0 = dst + ((size_t)e * C + c0 + rl) * R + r0 + cq;
#pragma unroll
  for (int i = 0; i < 2; i++) {
    ushort4 v;
    v.x = f2bf(tile[cq + 4 * i + 0][rl]);
    v.y = f2bf(tile[cq + 4 * i + 1][rl]);
    v.z = f2bf(tile[cq + 4 * i + 2][rl]);
    v.w = f2bf(tile[cq + 4 * i + 3][rl]);
    *(ushort4*)(d0 + 4 * i) = v;
  }
}

// Grouped expert GEMM (R6-proven core), 8 waves, LDS-staged B (dbuf + XOR swizzle).
// Prologue: wave-0 shfl-scan of 256 cell counts (1 barrier), binary-search token lookup.
__global__ __launch_bounds__(512) void moe_gemm_kernel(
    const unsigned short* __restrict__ xb,
    const unsigned short* __restrict__ keysT,
    const unsigned short* __restrict__ valuesT,
    const int* __restrict__ ccnt,
    const int* __restrict__ etok,
    const float* __restrict__ ew,
    unsigned short* __restrict__ yb) {
  const int e = blockIdx.x;
  const int base = blockIdx.y * 64;

  __shared__ int csc[NRB];
  __shared__ int cnt_s;
  __shared__ unsigned short stage_buf[2][8192];
  __shared__ unsigned short h_swz[8192];  // GEMM1 h tile; reused as y-chunk LDS in GEMM2
  __shared__ int tok_s[64];
  __shared__ int srow_s[64];
  __shared__ float w_s[64];

  const int tid = threadIdx.x;
  const int lane = tid & 63;
  const int wv = tid >> 6;

  // wave-0 inclusive scan of this expert's 256 cell counts (int4/lane + shfl)
  if (wv == 0) {
    int4 c4 = *(const int4*)(ccnt + e * NRB + lane * 4);
    int s0 = c4.x, s1 = s0 + c4.y, s2 = s1 + c4.z, s3 = s2 + c4.w;
    int tot = s3;
    for (int off = 1; off < 64; off <<= 1) {
      int n = __shfl_up(tot, off);
      if (lane >= off) tot += n;
    }
    int b0 = tot - s3;
    csc[lane * 4 + 0] = b0 + s0;
    csc[lane * 4 + 1] = b0 + s1;
    csc[lane * 4 + 2] = b0 + s2;
    csc[lane * 4 + 3] = b0 + s3;
    if (lane == 63) cnt_s = tot;
  }
  __syncthreads();
  const int cnt = cnt_s;
  if (base >= cnt) return;

  const int wm = wv & 3;
  const int wn = wv >> 2;
  const int ll = lane & 15, lh = lane >> 4;

  const unsigned short* kT = keysT + (size_t)e * HH * DD;
  const unsigned short* vT = valuesT + (size_t)e * DD * HH;

  auto stage_b1 = [&](int c, int b) {
#pragma unroll
    for (int i = 0; i < 2; i++) {
      int P = (i * 512 + tid) * 16;
      int n = P >> 7;
      int q = P & 127;
      const char* g = (const char*)(kT + (size_t)n * DD + c * 64) + (q ^ ((n & 7) << 4));
      char* l = (char*)stage_buf[b] + (i * 512 + (tid & ~63)) * 16;
      GLD16(g, l);
    }
  };
  auto stage_b2 = [&](int c, int b) {
#pragma unroll
    for (int i = 0; i < 2; i++) {
      int P = (i * 512 + tid) * 16;
      int r = P >> 8;
      int q = P & 255;
      const char* g = (const char*)(vT + (size_t)(c * 64 + r) * HH) + (q ^ ((r & 7) << 4));
      char* l = (char*)stage_buf[b] + (i * 512 + (tid & ~63)) * 16;
      GLD16(g, l);
    }
  };

  stage_b1(0, 0);
  if (tid < 64) {
    int i = base + tid;
    bool valid = i < cnt;
    int ie = valid ? i : (cnt - 1);
    int lo = 0, hi = NRB - 1;
    while (lo < hi) { int mid = (lo + hi) >> 1; if (csc[mid] > ie) hi = mid; else lo = mid + 1; }
    int prev = lo ? csc[lo - 1] : 0;
    size_t cell = ((size_t)e * NRB + lo) * 32 + (ie - prev);
    int v = etok[cell];
    int t = v & 0xFFFFF;
    tok_s[tid] = t;
    srow_s[tid] = valid ? ((v >> 20) * (TT + 1) + t) : TT;  // dump row when padding
    w_s[tid] = valid ? ew[cell] : 0.f;
  }
  __syncthreads();

  const unsigned short* ap = xb + (size_t)tok_s[wm * 16 + ll] * DD;

  f32x4 acc[4];
#pragma unroll
  for (int n = 0; n < 4; n++) { acc[n][0] = 0.f; acc[n][1] = 0.f; acc[n][2] = 0.f; acc[n][3] = 0.f; }

  for (int c = 0; c < 8; c++) {
    if (c < 7) stage_b1(c + 1, (c + 1) & 1);
    else       stage_b2(0, 0);
    const char* sb = (const char*)stage_buf[c & 1];
#pragma unroll
    for (int kkl = 0; kkl < 2; kkl++) {
      bf16x8 af = *(const bf16x8*)(ap + c * 64 + kkl * 32 + lh * 8);
#pragma unroll
      for (int nt = 0; nt < 4; nt++) {
        int n = wn * 64 + nt * 16 + ll;
        int boff = n * 128 + ((kkl * 64 + lh * 16) ^ ((n & 7) << 4));
        bf16x8 bfr = *(const bf16x8*)(sb + boff);
        acc[nt] = __builtin_amdgcn_mfma_f32_16x16x32_bf16(af, bfr, acc[nt], 0, 0, 0);
      }
    }
    __syncthreads();
  }

#pragma unroll
  for (int nt = 0; nt < 4; nt++) {
#pragma unroll
    for (int r = 0; r < 4; r++) {
      int row = wm * 16 + lh * 4 + r;
      int col = wn * 64 + nt * 16 + ll;
      int off = row * 256 + ((col * 2) ^ ((row & 7) << 4));
      *(unsigned short*)((char*)h_swz + off) = f2bf(fmaxf(acc[nt][r], 0.f));
    }
  }
  __syncthreads();

  bf16x8 a2[4];
#pragma unroll
  for (int kk = 0; kk < 4; kk++) {
    int row = wm * 16 + ll;
    int off = row * 256 + ((kk * 64 + lh * 16) ^ ((row & 7) << 4));
    a2[kk] = *(const bf16x8*)((const char*)h_swz + off);
  }

  float wr[4];
#pragma unroll
  for (int r = 0; r < 4; r++) wr[r] = w_s[wm * 16 + lh * 4 + r];

  __syncthreads();  // all a2 reads done; h_swz reusable as y_lds
  unsigned short* y_lds = h_swz;

  for (int c = 0; c < 8; c++) {
    if (c < 7) stage_b2(c + 1, (c + 1) & 1);
    const char* sb = (const char*)stage_buf[c & 1];
#pragma unroll
    for (int ntl = 0; ntl < 2; ntl++) {
      f32x4 c2;
      c2[0] = 0.f; c2[1] = 0.f; c2[2] = 0.f; c2[3] = 0.f;
#pragma unroll
      for (int kk = 0; kk < 4; kk++) {
        int r = wn * 32 + ntl * 16 + ll;
        int boff = r * 256 + ((kk * 64 + lh * 16) ^ ((r & 7) << 4));
        bf16x8 bfr = *(const bf16x8*)(sb + boff);
        c2 = __builtin_amdgcn_mfma_f32_16x16x32_bf16(a2[kk], bfr, c2, 0, 0, 0);
      }
      int colb = wn * 32 + ntl * 16 + ll;  // 0..63 within this c-chunk
#pragma unroll
      for (int r = 0; r < 4; r++) {
        int row = wm * 16 + lh * 4 + r;
        int off = row * 128 + ((colb * 2) ^ ((row & 7) << 4));
        *(unsigned short*)((char*)y_lds + off) = f2bf(c2[r] * wr[r]);
      }
    }
    __syncthreads();
    {
      int rr = tid >> 3, g = tid & 7;
      int off = rr * 128 + ((g * 16) ^ ((rr & 7) << 4));
      u16x8 v = *(const u16x8*)((const char*)y_lds + off);
      *(u16x8*)(yb + (size_t)srow_s[rr] * DD + c * 64 + g * 8) = v;
    }
    __syncthreads();
  }
}

// out[t][d] = ybuf[0][t][d] + ybuf[1][t][d]  (bf16 in, f32 out)
__global__ __launch_bounds__(256) void combine_kernel(const unsigned short* __restrict__ yb,
                                                      float* __restrict__ out) {
  size_t i = ((size_t)blockIdx.x * 256 + threadIdx.x) * 8;
  u16x8 a = *(const u16x8*)(yb + i);
  u16x8 b = *(const u16x8*)(yb + (size_t)(TT + 1) * DD + i);
  float4 o0, o1;
  o0.x = bf2f(a[0]) + bf2f(b[0]);
  o0.y = bf2f(a[1]) + bf2f(b[1]);
  o0.z = bf2f(a[2]) + bf2f(b[2]);
  o0.w = bf2f(a[3]) + bf2f(b[3]);
  o1.x = bf2f(a[4]) + bf2f(b[4]);
  o1.y = bf2f(a[5]) + bf2f(b[5]);
  o1.z = bf2f(a[6]) + bf2f(b[6]);
  o1.w = bf2f(a[7]) + bf2f(b[7]);
  *(float4*)(out + i) = o0;
  *(float4*)(out + i + 4) = o1;
}

extern "C" void kernel_launch(void* const* d_in, const int* in_sizes, int n_in,
                              void* d_out, int out_size, void* d_ws, size_t ws_size,
                              hipStream_t stream) {
  const float* x = (const float*)d_in[0];
  const float* esel = (const float*)d_in[1];
  const float* keys = (const float*)d_in[2];
  const float* values = (const float*)d_in[3];
  float* out = (float*)d_out;

  char* p = (char*)d_ws;
  unsigned short* xb = (unsigned short*)p;      p += (size_t)TT * DD * 2;
  unsigned short* keysT = (unsigned short*)p;   p += (size_t)EE * DD * HH * 2;
  unsigned short* valuesT = (unsigned short*)p; p += (size_t)EE * DD * HH * 2;
  int* ccnt = (int*)p;                          p += (size_t)EE * NRB * 4;
  int* etok = (int*)p;                          p += (size_t)EE * NRB * 32 * 4;
  float* ew = (float*)p;                        p += (size_t)EE * NRB * 32 * 4;
  unsigned short* yb = (unsigned short*)p;      p += (size_t)2 * (TT + 1) * DD * 2;

  prep_kernel<<<NRB + 1024, 512, 0, stream>>>(x, esel, keys, values, keysT, valuesT,
                                              xb, ccnt, etok, ew);
  moe_gemm_kernel<<<dim3(EE, TT / 64), 512, 0, stream>>>(xb, keysT, valuesT, ccnt, etok, ew, yb);
  combine_kernel<<<(TT * DD / 8) / 256, 256, 0, stream>>>(yb, out);
}